// Round 5
// baseline (1643.414 us; speedup 1.0000x reference)
//
#include <hip/hip_runtime.h>
#include <hip/hip_bf16.h>
#include <stdint.h>

#define NRAYS 1048576
#define INFV  1e9f

typedef short short8 __attribute__((ext_vector_type(8)));
typedef float f32x4  __attribute__((ext_vector_type(4)));

// ---- d_ws u32 layout ----
#define WS_B0   16     // 64 f32
#define WS_BS0  80     // 64 f32 (bs[0]); bs[1] at 144
#define WS_BS1  144
#define WS_G1   208    // ln_g[0]; ln_g[1] at 272
#define WS_G2   272
#define WS_H1   336    // ln_b[0]; ln_b[1] at 400
#define WS_H2   400
#define WS_WC   464
#define WS_WD   528
#define FB0     1024   // L0 frags: 4ct*3h*16lane*4 = 768 u32 (quad0 only)
#define FB1     2048   // L1+L2 frags: 2*(4ct*2kc*3h*64lane*4) = 12288 u32

#define PKLO(a,b) ((int)(((unsigned)(a) & 0xFFFFu) | ((unsigned)(b) << 16)))
#define PKHI(a,b) ((int)(((unsigned)(a) >> 16) | ((unsigned)(b) & 0xFFFF0000u)))

__device__ __forceinline__ float ldf(const void* p, int i, int fm) {
    if (fm) return ((const float*)p)[i];
    unsigned u = ((const unsigned short*)p)[i];
    return __uint_as_float(u << 16);
}

// split f32 into 3 truncated-bf16 components: him = hi(low16)|mid(high16), lo = lo(low16)
__device__ __forceinline__ void split3(float f, int& him, int& lo) {
    unsigned u = __float_as_uint(f);
    float r = f - __uint_as_float(u & 0xFFFF0000u);
    unsigned um = __float_as_uint(r);
    float r2 = r - __uint_as_float(um & 0xFFFF0000u);
    unsigned ul = __float_as_uint(r2);
    him = (int)((u >> 16) | (um & 0xFFFF0000u));
    lo  = (int)(ul >> 16);
}

__device__ __forceinline__ unsigned comp16(int h, float f) {
    unsigned u = __float_as_uint(f);
    if (h == 0) return u >> 16;
    float r = f - __uint_as_float(u & 0xFFFF0000u);
    unsigned um = __float_as_uint(r);
    if (h == 1) return um >> 16;
    float r2 = r - __uint_as_float(um & 0xFFFF0000u);
    return __float_as_uint(r2) >> 16;
}

__device__ __forceinline__ int bpi(int v, int lane) {
    return __builtin_amdgcn_ds_bpermute(lane << 2, v);
}
__device__ __forceinline__ float bpf(float v, int lane) {
    return __int_as_float(bpi(__float_as_int(v), lane));
}

// sum over the 16-lane DPP row (all lanes get the result) — VALU-pipe only
__device__ __forceinline__ float rsum16(float x) {
    int v;
    v = __builtin_amdgcn_update_dpp(0, __float_as_int(x), 0x128, 0xF, 0xF, false); x += __int_as_float(v); // ror:8
    v = __builtin_amdgcn_update_dpp(0, __float_as_int(x), 0x124, 0xF, 0xF, false); x += __int_as_float(v); // ror:4
    v = __builtin_amdgcn_update_dpp(0, __float_as_int(x), 0x122, 0xF, 0xF, false); x += __int_as_float(v); // ror:2
    v = __builtin_amdgcn_update_dpp(0, __float_as_int(x), 0x121, 0xF, 0xF, false); x += __int_as_float(v); // ror:1
    return x;
}

union I4S8 { int4 i; short8 s; };
__device__ __forceinline__ short8 mk8i(int a, int b, int c, int d) {
    I4S8 u; u.i = make_int4(a, b, c, d); return u.s;
}
__device__ __forceinline__ short8 ld_frag(const unsigned* p) {
    I4S8 u; u.i = *(const int4*)p; return u.s;
}

// ---------------- prologue: sniff dtypes, build f32 aux + bf16x3 W-fragments ----------------
__global__ __launch_bounds__(256) void conv_k(
    const void* __restrict__ mmin, const void* __restrict__ mmax,
    const void* __restrict__ masks,
    const void* __restrict__ W0, const void* __restrict__ b0,
    const void* __restrict__ lng, const void* __restrict__ lnb,
    const void* __restrict__ Ws, const void* __restrict__ bs,
    const void* __restrict__ Wc, const void* __restrict__ bc,
    const void* __restrict__ Wd, const void* __restrict__ bd,
    unsigned* __restrict__ ws)
{
    __shared__ int sfm;
    float* wf = (float*)ws;
    const int tid = threadIdx.x;
    if (tid == 0) {
        unsigned w0 = ((const unsigned*)mmin)[0];
        int fm = ((w0 & 0xFFFFu) == 0u) ? 1 : 0;
        const unsigned* mw = (const unsigned*)masks;
        bool sawBf = false, allBin = true, sawF32 = false;
        for (int i = 0; i < 64; ++i) {
            unsigned w = mw[i], lo = w & 0xFFFFu, hi = w >> 16;
            if (lo == 0x3F80u && (hi == 0x3F80u || hi == 0u)) sawBf = true;
            if (w == 0x3F800000u) sawF32 = true;
            if (w > 1u) allBin = false;
        }
        int ms = sawBf ? 2 : (allBin ? 4 : (sawF32 ? 4 : 1));
        ws[8] = (unsigned)fm; ws[9] = (unsigned)ms;
        for (int c = 0; c < 3; ++c) {
            float mn = ldf(mmin, c, fm), mx = ldf(mmax, c, fm);
            float ext = mx - mn;
            wf[c]     = mn - 0.5f * ext;
            wf[3 + c] = 1.0f / (2.0f * ext);
        }
        wf[6] = ldf(bc, 0, fm);
        wf[7] = ldf(bd, 0, fm);
        sfm = fm;
    }
    __syncthreads();
    const int fm = sfm;

    for (int i = tid; i < 64;  i += 256) { wf[WS_B0 + i] = ldf(b0, i, fm); wf[WS_WC + i] = ldf(Wc, i, fm); wf[WS_WD + i] = ldf(Wd, i, fm); }
    for (int i = tid; i < 128; i += 256) { wf[WS_BS0 + i] = ldf(bs, i, fm); wf[WS_G1 + i] = ldf(lng, i, fm); wf[WS_H1 + i] = ldf(lnb, i, fm); }

    // L0 collapsed weights W6[6][64]: rows 0..2 = sum_p W0[3p+c3], rows 3..5 = sum_p t_p W0[3p+c3]
    for (int w = tid; w < 768; w += 256) {
        int ct = w / 192, rem = w % 192;
        int h = rem / 64, wi = rem % 64;
        int lane16 = wi >> 2, p = wi & 3;
        int n = ct * 16 + lane16;
        unsigned word = 0;
        #pragma unroll
        for (int half = 0; half < 2; ++half) {
            int k = 2 * p + half;
            float v = 0.f;
            if (k < 3) {
                for (int pp = 0; pp < 8; ++pp) v += ldf(W0, (3 * pp + k) * 64 + n, fm);
            } else if (k < 6) {
                int c3 = k - 3;
                for (int pp = 0; pp < 8; ++pp) v = fmaf((float)((double)pp / 7.0), ldf(W0, (3 * pp + c3) * 64 + n, fm), v);
            }
            word |= comp16(h, v) << (16 * half);
        }
        ws[FB0 + ((ct * 3 + h) * 16 + lane16) * 4 + p] = word;
    }

    // L1/L2 fragments
    for (int w = tid; w < 12288; w += 256) {
        int li = w / 6144, inner = w % 6144;
        int t = inner >> 8;
        int h = t % 3, ckc = t / 3, kc = ckc & 1, ct = ckc >> 1;
        int wi = inner & 255, lane = wi >> 2, p = wi & 3;
        int qq = lane >> 4, cc = lane & 15;
        int n = ct * 16 + cc;
        int k0 = kc * 32 + qq * 8 + 2 * p;
        float f0 = ldf(Ws, li * 4096 + k0 * 64 + n, fm);
        float f1 = ldf(Ws, li * 4096 + (k0 + 1) * 64 + n, fm);
        ws[FB1 + w] = comp16(h, f0) | (comp16(h, f1) << 16);
    }
}

// ---------------- main: 64 rays/wave, MFMA bf16x3, 4 iters per pass ----------------
__global__ __launch_bounds__(64, 2) void nbvh_main(
    const void* __restrict__ orig_p, const void* __restrict__ vec_p,
    const void* __restrict__ masks_p, const void* __restrict__ t1_p,
    const void* __restrict__ t2_p, const unsigned* __restrict__ wsu,
    void* __restrict__ out_p)
{
    __shared__ __align__(16) unsigned sT1[4][16][64];  // hi|mid (16 KB)
    __shared__ __align__(16) unsigned sT2[4][16][32];  // lo pairs (delta | delta+32) (8 KB)
    __shared__ float sDf[64];

    const float* wf = (const float*)wsu;
    const int fm = (int)wsu[8];
    const int ms = (int)wsu[9];
    const float mn0 = wf[0], mn1 = wf[1], mn2 = wf[2];
    const float is0 = wf[3], is1 = wf[4], is2 = wf[5];
    const float bcv = wf[6], bdv = wf[7];

    const int L = threadIdx.x;
    const int q = L >> 4, c = L & 15;
    const int R0 = blockIdx.x * 64;
    const int ray = R0 + L;

    float b0v[4], s0v[4], s1v[4], g1v[4], h1v[4], g2v[4], h2v[4], wcv[4], wdv[4];
    #pragma unroll
    for (int ct = 0; ct < 4; ++ct) {
        int idx = ct * 16 + c;
        b0v[ct] = wf[WS_B0 + idx];
        s0v[ct] = wf[WS_BS0 + idx]; s1v[ct] = wf[WS_BS1 + idx];
        g1v[ct] = wf[WS_G1 + idx];  g2v[ct] = wf[WS_G2 + idx];
        h1v[ct] = wf[WS_H1 + idx];  h2v[ct] = wf[WS_H2 + idx];
        wcv[ct] = wf[WS_WC + idx];  wdv[ct] = wf[WS_WD + idx];
    }

    const float ox = ldf(orig_p, 3*ray+0, fm), oy = ldf(orig_p, 3*ray+1, fm), oz = ldf(orig_p, 3*ray+2, fm);
    const float vx = ldf(vec_p,  3*ray+0, fm), vy = ldf(vec_p,  3*ray+1, fm), vz = ldf(vec_p,  3*ray+2, fm);

    float x6f[4][6], ct1o[4], mko[4];
    #pragma unroll
    for (int it = 0; it < 4; ++it) {
        const int gi = it * NRAYS + ray;
        bool mk;
        if      (ms == 1) mk = ((const uint8_t*) masks_p)[gi] != 0;
        else if (ms == 2) mk = ((const uint16_t*)masks_p)[gi] != 0;
        else              mk = ((const unsigned*) masks_p)[gi] != 0;
        const float tt1 = ldf(t1_p, gi, fm), tt2 = ldf(t2_p, gi, fm);
        const float dt = tt2 - tt1;
        x6f[it][0] = (fmaf(vx, tt1, ox) - mn0) * is0;
        x6f[it][1] = (fmaf(vy, tt1, oy) - mn1) * is1;
        x6f[it][2] = (fmaf(vz, tt1, oz) - mn2) * is2;
        x6f[it][3] = (vx * dt) * is0;
        x6f[it][4] = (vy * dt) * is1;
        x6f[it][5] = (vz * dt) * is2;
        ct1o[it] = tt1;
        mko[it]  = mk ? 1.f : 0.f;
    }

    sDf[L] = INFV;
    __syncthreads();

    #pragma unroll 1
    for (int rt = 0; rt < 4; ++rt) {
        f32x4 acc[4][4];   // [it][ct]
        short8 Ah[4], Am[4], Al[4];

        // ---------- Layer 0 (k=6 collapsed) ----------
        #pragma unroll
        for (int it = 0; it < 4; ++it)
            #pragma unroll
            for (int ct = 0; ct < 4; ++ct) { f32x4 a; a[0]=a[1]=a[2]=a[3]=b0v[ct]; acc[it][ct]=a; }

        #pragma unroll
        for (int it = 0; it < 4; ++it) {
            int him[6], lo[6];
            #pragma unroll
            for (int j = 0; j < 6; ++j) {
                // FIX vs round 4: bpermute must run with FULL exec (uniform flow).
                // The old `(q==0) ? bpi(...) : 0` exec-masked the wave to lanes
                // 0..15, so for rt>=1 the source lanes (16..63) were inactive ->
                // undefined data. Execute on all lanes, then zero q!=0.
                int av = bpi(__float_as_int(x6f[it][j]), rt * 16 + c);
                if (q != 0) av = 0;
                split3(__int_as_float(av), him[j], lo[j]);
            }
            Ah[it] = mk8i(PKLO(him[0],him[1]), PKLO(him[2],him[3]), PKLO(him[4],him[5]), 0);
            Am[it] = mk8i(PKHI(him[0],him[1]), PKHI(him[2],him[3]), PKHI(him[4],him[5]), 0);
            Al[it] = mk8i(PKLO(lo[0], lo[1]),  PKLO(lo[2], lo[3]),  PKLO(lo[4], lo[5]),  0);
        }
        #pragma unroll
        for (int ct = 0; ct < 4; ++ct) {
            short8 Bh = (q==0) ? ld_frag(wsu + FB0 + ((ct*3+0)*16 + c)*4) : mk8i(0,0,0,0);
            short8 Bm = (q==0) ? ld_frag(wsu + FB0 + ((ct*3+1)*16 + c)*4) : mk8i(0,0,0,0);
            short8 Bl = (q==0) ? ld_frag(wsu + FB0 + ((ct*3+2)*16 + c)*4) : mk8i(0,0,0,0);
            #pragma unroll
            for (int it = 0; it < 4; ++it) {
                acc[it][ct] = __builtin_amdgcn_mfma_f32_16x16x32_bf16(Ah[it], Bh, acc[it][ct], 0,0,0);
                acc[it][ct] = __builtin_amdgcn_mfma_f32_16x16x32_bf16(Ah[it], Bm, acc[it][ct], 0,0,0);
                acc[it][ct] = __builtin_amdgcn_mfma_f32_16x16x32_bf16(Am[it], Bh, acc[it][ct], 0,0,0);
                acc[it][ct] = __builtin_amdgcn_mfma_f32_16x16x32_bf16(Am[it], Bm, acc[it][ct], 0,0,0);
                acc[it][ct] = __builtin_amdgcn_mfma_f32_16x16x32_bf16(Ah[it], Bl, acc[it][ct], 0,0,0);
                acc[it][ct] = __builtin_amdgcn_mfma_f32_16x16x32_bf16(Al[it], Bh, acc[it][ct], 0,0,0);
            }
        }

        // ---------- relu -> LN -> stage (x2 layers) + matmul ----------
        #pragma unroll
        for (int layer = 0; layer < 2; ++layer) {
            const float* gv = layer ? g2v : g1v;
            const float* hv = layer ? h2v : h1v;
            const float* bv = layer ? s1v : s0v;
            const unsigned* fb = wsu + FB1 + layer * 6144;

            __syncthreads();   // prior reads of sT done
            #pragma unroll
            for (int it = 0; it < 4; ++it) {
                float z[4][4], mu[4], rs[4];
                #pragma unroll
                for (int ct = 0; ct < 4; ++ct)
                    #pragma unroll
                    for (int e = 0; e < 4; ++e) z[ct][e] = fmaxf(acc[it][ct][e], 0.f);
                #pragma unroll
                for (int e = 0; e < 4; ++e) {
                    float s = z[0][e] + z[1][e] + z[2][e] + z[3][e];
                    mu[e] = rsum16(s) * (1.0f / 64.0f);
                }
                #pragma unroll
                for (int e = 0; e < 4; ++e) {
                    float d0 = z[0][e]-mu[e], d1 = z[1][e]-mu[e], d2 = z[2][e]-mu[e], d3 = z[3][e]-mu[e];
                    float vv = fmaf(d3,d3, fmaf(d2,d2, fmaf(d1,d1, d0*d0)));
                    vv = rsum16(vv);
                    rs[e] = rsqrtf(fmaf(vv, 1.0f / 64.0f, 1e-5f));
                }
                int him[4][4], lov[4][4];
                #pragma unroll
                for (int ct = 0; ct < 4; ++ct)
                    #pragma unroll
                    for (int e = 0; e < 4; ++e) {
                        float y = fmaf((z[ct][e] - mu[e]) * rs[e], gv[ct], hv[ct]);
                        split3(y, him[ct][e], lov[ct][e]);
                    }
                #pragma unroll
                for (int e = 0; e < 4; ++e) {
                    int row = q * 4 + e;
                    #pragma unroll
                    for (int ct = 0; ct < 4; ++ct) sT1[it][row][c + 16*ct] = (unsigned)him[ct][e];
                    sT2[it][row][c]      = (unsigned)PKLO(lov[0][e], lov[2][e]);
                    sT2[it][row][c + 16] = (unsigned)PKLO(lov[1][e], lov[3][e]);
                }
            }
            __syncthreads();

            #pragma unroll
            for (int it = 0; it < 4; ++it)
                #pragma unroll
                for (int ct = 0; ct < 4; ++ct) { f32x4 a; a[0]=a[1]=a[2]=a[3]=bv[ct]; acc[it][ct]=a; }

            #pragma unroll
            for (int kc = 0; kc < 2; ++kc) {
                #pragma unroll
                for (int it = 0; it < 4; ++it) {
                    const int4 w01 = *(const int4*)&sT1[it][c][kc*32 + q*8];
                    const int4 w23 = *(const int4*)&sT1[it][c][kc*32 + q*8 + 4];
                    const int4 t01 = *(const int4*)&sT2[it][c][q*8];
                    const int4 t23 = *(const int4*)&sT2[it][c][q*8 + 4];
                    Ah[it] = mk8i(PKLO(w01.x,w01.y), PKLO(w01.z,w01.w), PKLO(w23.x,w23.y), PKLO(w23.z,w23.w));
                    Am[it] = mk8i(PKHI(w01.x,w01.y), PKHI(w01.z,w01.w), PKHI(w23.x,w23.y), PKHI(w23.z,w23.w));
                    Al[it] = (kc == 0)
                        ? mk8i(PKLO(t01.x,t01.y), PKLO(t01.z,t01.w), PKLO(t23.x,t23.y), PKLO(t23.z,t23.w))
                        : mk8i(PKHI(t01.x,t01.y), PKHI(t01.z,t01.w), PKHI(t23.x,t23.y), PKHI(t23.z,t23.w));
                }
                #pragma unroll
                for (int ct = 0; ct < 4; ++ct) {
                    short8 Bh = ld_frag(fb + (((ct*2+kc)*3 + 0) << 8) + (L << 2));
                    short8 Bm = ld_frag(fb + (((ct*2+kc)*3 + 1) << 8) + (L << 2));
                    short8 Bl = ld_frag(fb + (((ct*2+kc)*3 + 2) << 8) + (L << 2));
                    #pragma unroll
                    for (int it = 0; it < 4; ++it) {
                        acc[it][ct] = __builtin_amdgcn_mfma_f32_16x16x32_bf16(Ah[it], Bh, acc[it][ct], 0,0,0);
                        acc[it][ct] = __builtin_amdgcn_mfma_f32_16x16x32_bf16(Ah[it], Bm, acc[it][ct], 0,0,0);
                        acc[it][ct] = __builtin_amdgcn_mfma_f32_16x16x32_bf16(Am[it], Bh, acc[it][ct], 0,0,0);
                        acc[it][ct] = __builtin_amdgcn_mfma_f32_16x16x32_bf16(Am[it], Bm, acc[it][ct], 0,0,0);
                        acc[it][ct] = __builtin_amdgcn_mfma_f32_16x16x32_bf16(Ah[it], Bl, acc[it][ct], 0,0,0);
                        acc[it][ct] = __builtin_amdgcn_mfma_f32_16x16x32_bf16(Al[it], Bh, acc[it][ct], 0,0,0);
                    }
                }
            }
        }

        // ---------- heads + dist update (C/D layout) ----------
        #pragma unroll
        for (int e = 0; e < 4; ++e) {
            const int idx = rt * 16 + q * 4 + e;
            float d = sDf[idx];
            #pragma unroll
            for (int it = 0; it < 4; ++it) {
                float cp = 0.f, dp = 0.f;
                #pragma unroll
                for (int ct = 0; ct < 4; ++ct) {
                    float f = fmaxf(acc[it][ct][e], 0.f);
                    cp = fmaf(f, wcv[ct], cp);
                    dp = fmaf(f, wdv[ct], dp);
                }
                cp = rsum16(cp); dp = rsum16(dp);
                float cls = cp + bcv;
                float t1v = bpf(ct1o[it], idx);
                float mkv = bpf(mko[it], idx);
                float dv  = dp + bdv + t1v;
                if (mkv > 0.5f && cls > 0.f && dv < d) d = dv;
            }
            if (c == 0) sDf[idx] = d;
        }
    }

    __syncthreads();
    float d = sDf[L];
    if (d == INFV) d = 0.f;
    const float hit = (d > 0.f) ? 1.f : 0.f;
    if (fm) {
        ((float*)out_p)[ray]         = hit;
        ((float*)out_p)[NRAYS + ray] = d;
    } else {
        __hip_bfloat16* o = (__hip_bfloat16*)out_p;
        o[ray]         = __float2bfloat16(hit);
        o[NRAYS + ray] = __float2bfloat16(d);
    }
}

extern "C" void kernel_launch(void* const* d_in, const int* in_sizes, int n_in,
                              void* d_out, int out_size, void* d_ws, size_t ws_size,
                              hipStream_t stream) {
    (void)in_sizes; (void)n_in; (void)ws_size; (void)out_size;
    unsigned* ws = (unsigned*)d_ws;
    conv_k<<<1, 256, 0, stream>>>(
        d_in[6], d_in[7], d_in[2],
        d_in[8], d_in[9], d_in[10], d_in[11],
        d_in[12], d_in[13], d_in[14], d_in[15],
        d_in[16], d_in[17], ws);
    nbvh_main<<<NRAYS / 64, 64, 0, stream>>>(
        d_in[0], d_in[1], d_in[2], d_in[4], d_in[5], ws, d_out);
}

// Round 6
// 1166.427 us; speedup vs baseline: 1.4089x; 1.4089x over previous
//
#include <hip/hip_runtime.h>
#include <hip/hip_bf16.h>
#include <stdint.h>

#define NRAYS 1048576
#define INFV  1e9f

typedef short short8 __attribute__((ext_vector_type(8)));
typedef float f32x4  __attribute__((ext_vector_type(4)));

// ---- d_ws u32 layout ----
#define WS_B0   16
#define WS_BS0  80
#define WS_BS1  144
#define WS_G1   208
#define WS_G2   272
#define WS_H1   336
#define WS_H2   400
#define WS_WC   464
#define WS_WD   528
#define FB0     1024   // L0 frags: 4ct*3h*16lane*4 = 768 u32 (quad0 only)
#define FB1     2048   // L1+L2 frags: 2*(4ct*2kc*3h*64lane*4) = 12288 u32

#define PKLO(a,b) ((int)(((unsigned)(a) & 0xFFFFu) | ((unsigned)(b) << 16)))
#define PKHI(a,b) ((int)(((unsigned)(a) >> 16) | ((unsigned)(b) & 0xFFFF0000u)))

__device__ __forceinline__ float ldf(const void* p, int i, int fm) {
    if (fm) return ((const float*)p)[i];
    unsigned u = ((const unsigned short*)p)[i];
    return __uint_as_float(u << 16);
}

__device__ __forceinline__ void split3(float f, int& him, int& lo) {
    unsigned u = __float_as_uint(f);
    float r = f - __uint_as_float(u & 0xFFFF0000u);
    unsigned um = __float_as_uint(r);
    float r2 = r - __uint_as_float(um & 0xFFFF0000u);
    unsigned ul = __float_as_uint(r2);
    him = (int)((u >> 16) | (um & 0xFFFF0000u));
    lo  = (int)(ul >> 16);
}

__device__ __forceinline__ unsigned comp16(int h, float f) {
    unsigned u = __float_as_uint(f);
    if (h == 0) return u >> 16;
    float r = f - __uint_as_float(u & 0xFFFF0000u);
    unsigned um = __float_as_uint(r);
    if (h == 1) return um >> 16;
    float r2 = r - __uint_as_float(um & 0xFFFF0000u);
    return __float_as_uint(r2) >> 16;
}

__device__ __forceinline__ int bpi(int v, int lane) {
    return __builtin_amdgcn_ds_bpermute(lane << 2, v);
}
__device__ __forceinline__ float bpf(float v, int lane) {
    return __int_as_float(bpi(__float_as_int(v), lane));
}

__device__ __forceinline__ float rsum16(float x) {
    int v;
    v = __builtin_amdgcn_update_dpp(0, __float_as_int(x), 0x128, 0xF, 0xF, false); x += __int_as_float(v);
    v = __builtin_amdgcn_update_dpp(0, __float_as_int(x), 0x124, 0xF, 0xF, false); x += __int_as_float(v);
    v = __builtin_amdgcn_update_dpp(0, __float_as_int(x), 0x122, 0xF, 0xF, false); x += __int_as_float(v);
    v = __builtin_amdgcn_update_dpp(0, __float_as_int(x), 0x121, 0xF, 0xF, false); x += __int_as_float(v);
    return x;
}

union I4S8 { int4 i; short8 s; };
__device__ __forceinline__ short8 mk8i(int a, int b, int c, int d) {
    I4S8 u; u.i = make_int4(a, b, c, d); return u.s;
}
__device__ __forceinline__ short8 ld_frag(const unsigned* p) {
    I4S8 u; u.i = *(const int4*)p; return u.s;
}

// ---------------- prologue (unchanged from round 5 — validated) ----------------
__global__ __launch_bounds__(256) void conv_k(
    const void* __restrict__ mmin, const void* __restrict__ mmax,
    const void* __restrict__ masks,
    const void* __restrict__ W0, const void* __restrict__ b0,
    const void* __restrict__ lng, const void* __restrict__ lnb,
    const void* __restrict__ Ws, const void* __restrict__ bs,
    const void* __restrict__ Wc, const void* __restrict__ bc,
    const void* __restrict__ Wd, const void* __restrict__ bd,
    unsigned* __restrict__ ws)
{
    __shared__ int sfm;
    float* wf = (float*)ws;
    const int tid = threadIdx.x;
    if (tid == 0) {
        unsigned w0 = ((const unsigned*)mmin)[0];
        int fm = ((w0 & 0xFFFFu) == 0u) ? 1 : 0;
        const unsigned* mw = (const unsigned*)masks;
        bool sawBf = false, allBin = true, sawF32 = false;
        for (int i = 0; i < 64; ++i) {
            unsigned w = mw[i], lo = w & 0xFFFFu, hi = w >> 16;
            if (lo == 0x3F80u && (hi == 0x3F80u || hi == 0u)) sawBf = true;
            if (w == 0x3F800000u) sawF32 = true;
            if (w > 1u) allBin = false;
        }
        int ms = sawBf ? 2 : (allBin ? 4 : (sawF32 ? 4 : 1));
        ws[8] = (unsigned)fm; ws[9] = (unsigned)ms;
        for (int c = 0; c < 3; ++c) {
            float mn = ldf(mmin, c, fm), mx = ldf(mmax, c, fm);
            float ext = mx - mn;
            wf[c]     = mn - 0.5f * ext;
            wf[3 + c] = 1.0f / (2.0f * ext);
        }
        wf[6] = ldf(bc, 0, fm);
        wf[7] = ldf(bd, 0, fm);
        sfm = fm;
    }
    __syncthreads();
    const int fm = sfm;

    for (int i = tid; i < 64;  i += 256) { wf[WS_B0 + i] = ldf(b0, i, fm); wf[WS_WC + i] = ldf(Wc, i, fm); wf[WS_WD + i] = ldf(Wd, i, fm); }
    for (int i = tid; i < 128; i += 256) { wf[WS_BS0 + i] = ldf(bs, i, fm); wf[WS_G1 + i] = ldf(lng, i, fm); wf[WS_H1 + i] = ldf(lnb, i, fm); }

    for (int w = tid; w < 768; w += 256) {
        int ct = w / 192, rem = w % 192;
        int h = rem / 64, wi = rem % 64;
        int lane16 = wi >> 2, p = wi & 3;
        int n = ct * 16 + lane16;
        unsigned word = 0;
        #pragma unroll
        for (int half = 0; half < 2; ++half) {
            int k = 2 * p + half;
            float v = 0.f;
            if (k < 3) {
                for (int pp = 0; pp < 8; ++pp) v += ldf(W0, (3 * pp + k) * 64 + n, fm);
            } else if (k < 6) {
                int c3 = k - 3;
                for (int pp = 0; pp < 8; ++pp) v = fmaf((float)((double)pp / 7.0), ldf(W0, (3 * pp + c3) * 64 + n, fm), v);
            }
            word |= comp16(h, v) << (16 * half);
        }
        ws[FB0 + ((ct * 3 + h) * 16 + lane16) * 4 + p] = word;
    }

    for (int w = tid; w < 12288; w += 256) {
        int li = w / 6144, inner = w % 6144;
        int t = inner >> 8;
        int h = t % 3, ckc = t / 3, kc = ckc & 1, ct = ckc >> 1;
        int wi = inner & 255, lane = wi >> 2, p = wi & 3;
        int qq = lane >> 4, cc = lane & 15;
        int n = ct * 16 + cc;
        int k0 = kc * 32 + qq * 8 + 2 * p;
        float f0 = ldf(Ws, li * 4096 + k0 * 64 + n, fm);
        float f1 = ldf(Ws, li * 4096 + (k0 + 1) * 64 + n, fm);
        ws[FB1 + w] = comp16(h, f0) | (comp16(h, f1) << 16);
    }
}

// ---------------- main: 64 rays/wave, MFMA bf16x3, 2 its per pass (reg fix),
// padded LDS strides (bank-conflict fix) ----------------
#define ST1_S 66   // padded from 64: rebuild reads 4-way, stores 2-way
#define ST2_S 34   // padded from 32

__global__ __launch_bounds__(64, 2) void nbvh_main(
    const void* __restrict__ orig_p, const void* __restrict__ vec_p,
    const void* __restrict__ masks_p, const void* __restrict__ t1_p,
    const void* __restrict__ t2_p, const unsigned* __restrict__ wsu,
    void* __restrict__ out_p)
{
    __shared__ __align__(16) unsigned sT1[2][16][ST1_S];  // hi|mid
    __shared__ __align__(16) unsigned sT2[2][16][ST2_S];  // lo pairs
    __shared__ float sDf[64];

    const float* wf = (const float*)wsu;
    const int fm = (int)wsu[8];
    const int ms = (int)wsu[9];
    const float mn0 = wf[0], mn1 = wf[1], mn2 = wf[2];
    const float is0 = wf[3], is1 = wf[4], is2 = wf[5];
    const float bcv = wf[6], bdv = wf[7];

    const int L = threadIdx.x;
    const int q = L >> 4, c = L & 15;
    const int ray = blockIdx.x * 64 + L;

    float b0v[4], s0v[4], s1v[4], g1v[4], h1v[4], g2v[4], h2v[4], wcv[4], wdv[4];
    #pragma unroll
    for (int ct = 0; ct < 4; ++ct) {
        int idx = ct * 16 + c;
        b0v[ct] = wf[WS_B0 + idx];
        s0v[ct] = wf[WS_BS0 + idx]; s1v[ct] = wf[WS_BS1 + idx];
        g1v[ct] = wf[WS_G1 + idx];  g2v[ct] = wf[WS_G2 + idx];
        h1v[ct] = wf[WS_H1 + idx];  h2v[ct] = wf[WS_H2 + idx];
        wcv[ct] = wf[WS_WC + idx];  wdv[ct] = wf[WS_WD + idx];
    }

    const float ox = ldf(orig_p, 3*ray+0, fm), oy = ldf(orig_p, 3*ray+1, fm), oz = ldf(orig_p, 3*ray+2, fm);
    const float vx = ldf(vec_p,  3*ray+0, fm), vy = ldf(vec_p,  3*ray+1, fm), vz = ldf(vec_p,  3*ray+2, fm);

    float x6f[4][6], ct1o[4], mko[4];
    #pragma unroll
    for (int it = 0; it < 4; ++it) {
        const int gi = it * NRAYS + ray;
        bool mk;
        if      (ms == 1) mk = ((const uint8_t*) masks_p)[gi] != 0;
        else if (ms == 2) mk = ((const uint16_t*)masks_p)[gi] != 0;
        else              mk = ((const unsigned*) masks_p)[gi] != 0;
        const float tt1 = ldf(t1_p, gi, fm), tt2 = ldf(t2_p, gi, fm);
        const float dt = tt2 - tt1;
        x6f[it][0] = (fmaf(vx, tt1, ox) - mn0) * is0;
        x6f[it][1] = (fmaf(vy, tt1, oy) - mn1) * is1;
        x6f[it][2] = (fmaf(vz, tt1, oz) - mn2) * is2;
        x6f[it][3] = (vx * dt) * is0;
        x6f[it][4] = (vy * dt) * is1;
        x6f[it][5] = (vz * dt) * is2;
        ct1o[it] = tt1;
        mko[it]  = mk ? 1.f : 0.f;
    }

    sDf[L] = INFV;
    __syncthreads();

    #pragma unroll 1
    for (int rt = 0; rt < 4; ++rt) {
        #pragma unroll            // ip MUST unroll: x6f/ct1o/mko need const idx
        for (int ip = 0; ip < 2; ++ip) {
            f32x4 acc[2][4];      // [itl][ct] — halved vs round 5 (spill fix)
            short8 Ah[2], Am[2], Al[2];

            // ---------- Layer 0 (k=6 collapsed) ----------
            #pragma unroll
            for (int itl = 0; itl < 2; ++itl)
                #pragma unroll
                for (int ct = 0; ct < 4; ++ct) { f32x4 a; a[0]=a[1]=a[2]=a[3]=b0v[ct]; acc[itl][ct]=a; }

            #pragma unroll
            for (int itl = 0; itl < 2; ++itl) {
                const int it = ip * 2 + itl;
                int him[6], lo[6];
                #pragma unroll
                for (int j = 0; j < 6; ++j) {
                    int av = bpi(__float_as_int(x6f[it][j]), rt * 16 + c);  // full-exec
                    if (q != 0) av = 0;
                    split3(__int_as_float(av), him[j], lo[j]);
                }
                Ah[itl] = mk8i(PKLO(him[0],him[1]), PKLO(him[2],him[3]), PKLO(him[4],him[5]), 0);
                Am[itl] = mk8i(PKHI(him[0],him[1]), PKHI(him[2],him[3]), PKHI(him[4],him[5]), 0);
                Al[itl] = mk8i(PKLO(lo[0], lo[1]),  PKLO(lo[2], lo[3]),  PKLO(lo[4], lo[5]),  0);
            }
            #pragma unroll
            for (int ct = 0; ct < 4; ++ct) {
                short8 Bh = (q==0) ? ld_frag(wsu + FB0 + ((ct*3+0)*16 + c)*4) : mk8i(0,0,0,0);
                short8 Bm = (q==0) ? ld_frag(wsu + FB0 + ((ct*3+1)*16 + c)*4) : mk8i(0,0,0,0);
                short8 Bl = (q==0) ? ld_frag(wsu + FB0 + ((ct*3+2)*16 + c)*4) : mk8i(0,0,0,0);
                #pragma unroll
                for (int itl = 0; itl < 2; ++itl) {
                    acc[itl][ct] = __builtin_amdgcn_mfma_f32_16x16x32_bf16(Ah[itl], Bh, acc[itl][ct], 0,0,0);
                    acc[itl][ct] = __builtin_amdgcn_mfma_f32_16x16x32_bf16(Ah[itl], Bm, acc[itl][ct], 0,0,0);
                    acc[itl][ct] = __builtin_amdgcn_mfma_f32_16x16x32_bf16(Am[itl], Bh, acc[itl][ct], 0,0,0);
                    acc[itl][ct] = __builtin_amdgcn_mfma_f32_16x16x32_bf16(Am[itl], Bm, acc[itl][ct], 0,0,0);
                    acc[itl][ct] = __builtin_amdgcn_mfma_f32_16x16x32_bf16(Ah[itl], Bl, acc[itl][ct], 0,0,0);
                    acc[itl][ct] = __builtin_amdgcn_mfma_f32_16x16x32_bf16(Al[itl], Bh, acc[itl][ct], 0,0,0);
                }
            }

            // ---------- relu -> LN -> stage -> matmul (x2 layers) ----------
            #pragma unroll
            for (int layer = 0; layer < 2; ++layer) {
                const float* gv = layer ? g2v : g1v;
                const float* hv = layer ? h2v : h1v;
                const float* bv = layer ? s1v : s0v;
                const unsigned* fb = wsu + FB1 + layer * 6144;

                __syncthreads();
                #pragma unroll
                for (int itl = 0; itl < 2; ++itl) {
                    float z[4][4], mu[4], rs[4];
                    #pragma unroll
                    for (int ct = 0; ct < 4; ++ct)
                        #pragma unroll
                        for (int e = 0; e < 4; ++e) z[ct][e] = fmaxf(acc[itl][ct][e], 0.f);
                    #pragma unroll
                    for (int e = 0; e < 4; ++e) {
                        float s = z[0][e] + z[1][e] + z[2][e] + z[3][e];
                        mu[e] = rsum16(s) * (1.0f / 64.0f);
                    }
                    #pragma unroll
                    for (int e = 0; e < 4; ++e) {
                        float d0 = z[0][e]-mu[e], d1 = z[1][e]-mu[e], d2 = z[2][e]-mu[e], d3 = z[3][e]-mu[e];
                        float vv = fmaf(d3,d3, fmaf(d2,d2, fmaf(d1,d1, d0*d0)));
                        vv = rsum16(vv);
                        rs[e] = rsqrtf(fmaf(vv, 1.0f / 64.0f, 1e-5f));
                    }
                    int him[4][4], lov[4][4];
                    #pragma unroll
                    for (int ct = 0; ct < 4; ++ct)
                        #pragma unroll
                        for (int e = 0; e < 4; ++e) {
                            float y = fmaf((z[ct][e] - mu[e]) * rs[e], gv[ct], hv[ct]);
                            split3(y, him[ct][e], lov[ct][e]);
                        }
                    #pragma unroll
                    for (int e = 0; e < 4; ++e) {
                        int row = q * 4 + e;
                        #pragma unroll
                        for (int ct = 0; ct < 4; ++ct) sT1[itl][row][c + 16*ct] = (unsigned)him[ct][e];
                        sT2[itl][row][c]      = (unsigned)PKLO(lov[0][e], lov[2][e]);
                        sT2[itl][row][c + 16] = (unsigned)PKLO(lov[1][e], lov[3][e]);
                    }
                }
                __syncthreads();

                #pragma unroll
                for (int itl = 0; itl < 2; ++itl)
                    #pragma unroll
                    for (int ct = 0; ct < 4; ++ct) { f32x4 a; a[0]=a[1]=a[2]=a[3]=bv[ct]; acc[itl][ct]=a; }

                #pragma unroll
                for (int kc = 0; kc < 2; ++kc) {
                    #pragma unroll
                    for (int itl = 0; itl < 2; ++itl) {
                        const int4 w01 = *(const int4*)&sT1[itl][c][kc*32 + q*8];
                        const int4 w23 = *(const int4*)&sT1[itl][c][kc*32 + q*8 + 4];
                        const int4 t01 = *(const int4*)&sT2[itl][c][q*8];
                        const int4 t23 = *(const int4*)&sT2[itl][c][q*8 + 4];
                        Ah[itl] = mk8i(PKLO(w01.x,w01.y), PKLO(w01.z,w01.w), PKLO(w23.x,w23.y), PKLO(w23.z,w23.w));
                        Am[itl] = mk8i(PKHI(w01.x,w01.y), PKHI(w01.z,w01.w), PKHI(w23.x,w23.y), PKHI(w23.z,w23.w));
                        Al[itl] = (kc == 0)
                            ? mk8i(PKLO(t01.x,t01.y), PKLO(t01.z,t01.w), PKLO(t23.x,t23.y), PKLO(t23.z,t23.w))
                            : mk8i(PKHI(t01.x,t01.y), PKHI(t01.z,t01.w), PKHI(t23.x,t23.y), PKHI(t23.z,t23.w));
                    }
                    #pragma unroll
                    for (int ct = 0; ct < 4; ++ct) {
                        short8 Bh = ld_frag(fb + (((ct*2+kc)*3 + 0) << 8) + (L << 2));
                        short8 Bm = ld_frag(fb + (((ct*2+kc)*3 + 1) << 8) + (L << 2));
                        short8 Bl = ld_frag(fb + (((ct*2+kc)*3 + 2) << 8) + (L << 2));
                        #pragma unroll
                        for (int itl = 0; itl < 2; ++itl) {
                            acc[itl][ct] = __builtin_amdgcn_mfma_f32_16x16x32_bf16(Ah[itl], Bh, acc[itl][ct], 0,0,0);
                            acc[itl][ct] = __builtin_amdgcn_mfma_f32_16x16x32_bf16(Ah[itl], Bm, acc[itl][ct], 0,0,0);
                            acc[itl][ct] = __builtin_amdgcn_mfma_f32_16x16x32_bf16(Am[itl], Bh, acc[itl][ct], 0,0,0);
                            acc[itl][ct] = __builtin_amdgcn_mfma_f32_16x16x32_bf16(Am[itl], Bm, acc[itl][ct], 0,0,0);
                            acc[itl][ct] = __builtin_amdgcn_mfma_f32_16x16x32_bf16(Ah[itl], Bl, acc[itl][ct], 0,0,0);
                            acc[itl][ct] = __builtin_amdgcn_mfma_f32_16x16x32_bf16(Al[itl], Bh, acc[itl][ct], 0,0,0);
                        }
                    }
                }
            }

            // ---------- heads + dist update (C/D layout) ----------
            #pragma unroll
            for (int e = 0; e < 4; ++e) {
                const int idx = rt * 16 + q * 4 + e;
                float d = sDf[idx];
                #pragma unroll
                for (int itl = 0; itl < 2; ++itl) {
                    const int it = ip * 2 + itl;
                    float cp = 0.f, dp = 0.f;
                    #pragma unroll
                    for (int ct = 0; ct < 4; ++ct) {
                        float f = fmaxf(acc[itl][ct][e], 0.f);
                        cp = fmaf(f, wcv[ct], cp);
                        dp = fmaf(f, wdv[ct], dp);
                    }
                    cp = rsum16(cp); dp = rsum16(dp);
                    float cls = cp + bcv;
                    float t1v = bpf(ct1o[it], idx);
                    float mkv = bpf(mko[it], idx);
                    float dv  = dp + bdv + t1v;
                    if (mkv > 0.5f && cls > 0.f && dv < d) d = dv;
                }
                if (c == 0) sDf[idx] = d;
            }
        }
    }

    __syncthreads();
    float d = sDf[L];
    if (d == INFV) d = 0.f;
    const float hit = (d > 0.f) ? 1.f : 0.f;
    if (fm) {
        ((float*)out_p)[ray]         = hit;
        ((float*)out_p)[NRAYS + ray] = d;
    } else {
        __hip_bfloat16* o = (__hip_bfloat16*)out_p;
        o[ray]         = __float2bfloat16(hit);
        o[NRAYS + ray] = __float2bfloat16(d);
    }
}

extern "C" void kernel_launch(void* const* d_in, const int* in_sizes, int n_in,
                              void* d_out, int out_size, void* d_ws, size_t ws_size,
                              hipStream_t stream) {
    (void)in_sizes; (void)n_in; (void)ws_size; (void)out_size;
    unsigned* ws = (unsigned*)d_ws;
    conv_k<<<1, 256, 0, stream>>>(
        d_in[6], d_in[7], d_in[2],
        d_in[8], d_in[9], d_in[10], d_in[11],
        d_in[12], d_in[13], d_in[14], d_in[15],
        d_in[16], d_in[17], ws);
    nbvh_main<<<NRAYS / 64, 64, 0, stream>>>(
        d_in[0], d_in[1], d_in[2], d_in[4], d_in[5], ws, d_out);
}

// Round 7
// 1014.372 us; speedup vs baseline: 1.6201x; 1.1499x over previous
//
#include <hip/hip_runtime.h>
#include <hip/hip_bf16.h>
#include <stdint.h>

#define NRAYS 1048576
#define INFV  1e9f

typedef short short8 __attribute__((ext_vector_type(8)));
typedef float f32x4  __attribute__((ext_vector_type(4)));

// ---- d_ws u32 layout ----
#define WS_B0   16
#define WS_BS0  80
#define WS_BS1  144
#define WS_G1   208
#define WS_G2   272
#define WS_H1   336
#define WS_H2   400
#define WS_WC   464
#define WS_WD   528
#define FB0     1024   // L0 frags: 4ct*3h*16lane*4 = 768 u32 (quad0 only)
#define FB1     2048   // L1+L2 frags: 2*(4ct*2kc*3h*64lane*4) = 12288 u32

#define PKLO(a,b) ((int)(((unsigned)(a) & 0xFFFFu) | ((unsigned)(b) << 16)))
#define PKHI(a,b) ((int)(((unsigned)(a) >> 16) | ((unsigned)(b) & 0xFFFF0000u)))

__device__ __forceinline__ float ldf(const void* p, int i, int fm) {
    if (fm) return ((const float*)p)[i];
    unsigned u = ((const unsigned short*)p)[i];
    return __uint_as_float(u << 16);
}

__device__ __forceinline__ void split3(float f, int& him, int& lo) {
    unsigned u = __float_as_uint(f);
    float r = f - __uint_as_float(u & 0xFFFF0000u);
    unsigned um = __float_as_uint(r);
    float r2 = r - __uint_as_float(um & 0xFFFF0000u);
    unsigned ul = __float_as_uint(r2);
    him = (int)((u >> 16) | (um & 0xFFFF0000u));
    lo  = (int)(ul >> 16);
}

__device__ __forceinline__ unsigned comp16(int h, float f) {
    unsigned u = __float_as_uint(f);
    if (h == 0) return u >> 16;
    float r = f - __uint_as_float(u & 0xFFFF0000u);
    unsigned um = __float_as_uint(r);
    if (h == 1) return um >> 16;
    float r2 = r - __uint_as_float(um & 0xFFFF0000u);
    return __float_as_uint(r2) >> 16;
}

__device__ __forceinline__ float rsum16(float x) {
    int v;
    v = __builtin_amdgcn_update_dpp(0, __float_as_int(x), 0x128, 0xF, 0xF, false); x += __int_as_float(v);
    v = __builtin_amdgcn_update_dpp(0, __float_as_int(x), 0x124, 0xF, 0xF, false); x += __int_as_float(v);
    v = __builtin_amdgcn_update_dpp(0, __float_as_int(x), 0x122, 0xF, 0xF, false); x += __int_as_float(v);
    v = __builtin_amdgcn_update_dpp(0, __float_as_int(x), 0x121, 0xF, 0xF, false); x += __int_as_float(v);
    return x;
}

union I4S8 { int4 i; short8 s; };
__device__ __forceinline__ short8 mk8i(int a, int b, int c, int d) {
    I4S8 u; u.i = make_int4(a, b, c, d); return u.s;
}
__device__ __forceinline__ short8 ld_frag(const unsigned* p) {
    I4S8 u; u.i = *(const int4*)p; return u.s;
}

// ---------------- prologue (unchanged — validated) ----------------
__global__ __launch_bounds__(256) void conv_k(
    const void* __restrict__ mmin, const void* __restrict__ mmax,
    const void* __restrict__ masks,
    const void* __restrict__ W0, const void* __restrict__ b0,
    const void* __restrict__ lng, const void* __restrict__ lnb,
    const void* __restrict__ Ws, const void* __restrict__ bs,
    const void* __restrict__ Wc, const void* __restrict__ bc,
    const void* __restrict__ Wd, const void* __restrict__ bd,
    unsigned* __restrict__ ws)
{
    __shared__ int sfm;
    float* wf = (float*)ws;
    const int tid = threadIdx.x;
    if (tid == 0) {
        unsigned w0 = ((const unsigned*)mmin)[0];
        int fm = ((w0 & 0xFFFFu) == 0u) ? 1 : 0;
        const unsigned* mw = (const unsigned*)masks;
        bool sawBf = false, allBin = true, sawF32 = false;
        for (int i = 0; i < 64; ++i) {
            unsigned w = mw[i], lo = w & 0xFFFFu, hi = w >> 16;
            if (lo == 0x3F80u && (hi == 0x3F80u || hi == 0u)) sawBf = true;
            if (w == 0x3F800000u) sawF32 = true;
            if (w > 1u) allBin = false;
        }
        int ms = sawBf ? 2 : (allBin ? 4 : (sawF32 ? 4 : 1));
        ws[8] = (unsigned)fm; ws[9] = (unsigned)ms;
        for (int c = 0; c < 3; ++c) {
            float mn = ldf(mmin, c, fm), mx = ldf(mmax, c, fm);
            float ext = mx - mn;
            wf[c]     = mn - 0.5f * ext;
            wf[3 + c] = 1.0f / (2.0f * ext);
        }
        wf[6] = ldf(bc, 0, fm);
        wf[7] = ldf(bd, 0, fm);
        sfm = fm;
    }
    __syncthreads();
    const int fm = sfm;

    for (int i = tid; i < 64;  i += 256) { wf[WS_B0 + i] = ldf(b0, i, fm); wf[WS_WC + i] = ldf(Wc, i, fm); wf[WS_WD + i] = ldf(Wd, i, fm); }
    for (int i = tid; i < 128; i += 256) { wf[WS_BS0 + i] = ldf(bs, i, fm); wf[WS_G1 + i] = ldf(lng, i, fm); wf[WS_H1 + i] = ldf(lnb, i, fm); }

    for (int w = tid; w < 768; w += 256) {
        int ct = w / 192, rem = w % 192;
        int h = rem / 64, wi = rem % 64;
        int lane16 = wi >> 2, p = wi & 3;
        int n = ct * 16 + lane16;
        unsigned word = 0;
        #pragma unroll
        for (int half = 0; half < 2; ++half) {
            int k = 2 * p + half;
            float v = 0.f;
            if (k < 3) {
                for (int pp = 0; pp < 8; ++pp) v += ldf(W0, (3 * pp + k) * 64 + n, fm);
            } else if (k < 6) {
                int c3 = k - 3;
                for (int pp = 0; pp < 8; ++pp) v = fmaf((float)((double)pp / 7.0), ldf(W0, (3 * pp + c3) * 64 + n, fm), v);
            }
            word |= comp16(h, v) << (16 * half);
        }
        ws[FB0 + ((ct * 3 + h) * 16 + lane16) * 4 + p] = word;
    }

    for (int w = tid; w < 12288; w += 256) {
        int li = w / 6144, inner = w % 6144;
        int t = inner >> 8;
        int h = t % 3, ckc = t / 3, kc = ckc & 1, ct = ckc >> 1;
        int wi = inner & 255, lane = wi >> 2, p = wi & 3;
        int qq = lane >> 4, cc = lane & 15;
        int n = ct * 16 + cc;
        int k0 = kc * 32 + qq * 8 + 2 * p;
        float f0 = ldf(Ws, li * 4096 + k0 * 64 + n, fm);
        float f1 = ldf(Ws, li * 4096 + (k0 + 1) * 64 + n, fm);
        ws[FB1 + w] = comp16(h, f0) | (comp16(h, f1) << 16);
    }
}

// ---------------- main: 64 rays/wave, MFMA bf16x3; per-ray state in LDS
// (register-pressure fix), launch_bounds(64,1) (raise arch-VGPR cap) ----------------
#define ST1_S 66
#define ST2_S 34

__global__ __launch_bounds__(64, 1) void nbvh_main(
    const void* __restrict__ orig_p, const void* __restrict__ vec_p,
    const void* __restrict__ masks_p, const void* __restrict__ t1_p,
    const void* __restrict__ t2_p, const unsigned* __restrict__ wsu,
    void* __restrict__ out_p)
{
    __shared__ __align__(16) unsigned sT1[2][16][ST1_S];  // hi|mid transpose
    __shared__ __align__(16) unsigned sT2[2][16][ST2_S];  // lo transpose
    __shared__ float sX[4][6][64];   // per-ray L0 inputs (was x6f[4][6] regs)
    __shared__ float sCT[4][64];     // per-ray t1      (was ct1o[4] regs)
    __shared__ float sMK[4][64];     // per-ray mask    (was mko[4] regs)
    __shared__ float sDf[64];

    const float* wf = (const float*)wsu;
    const int fm = (int)wsu[8];
    const int ms = (int)wsu[9];
    const float bcv = wf[6], bdv = wf[7];

    const int L = threadIdx.x;
    const int q = L >> 4, c = L & 15;
    const int ray = blockIdx.x * 64 + L;

    float b0v[4], s0v[4], s1v[4], g1v[4], h1v[4], g2v[4], h2v[4], wcv[4], wdv[4];
    #pragma unroll
    for (int ct = 0; ct < 4; ++ct) {
        int idx = ct * 16 + c;
        b0v[ct] = wf[WS_B0 + idx];
        s0v[ct] = wf[WS_BS0 + idx]; s1v[ct] = wf[WS_BS1 + idx];
        g1v[ct] = wf[WS_G1 + idx];  g2v[ct] = wf[WS_G2 + idx];
        h1v[ct] = wf[WS_H1 + idx];  h2v[ct] = wf[WS_H2 + idx];
        wcv[ct] = wf[WS_WC + idx];  wdv[ct] = wf[WS_WD + idx];
    }

    {
        const float mn0 = wf[0], mn1 = wf[1], mn2 = wf[2];
        const float is0 = wf[3], is1 = wf[4], is2 = wf[5];
        const float ox = ldf(orig_p, 3*ray+0, fm), oy = ldf(orig_p, 3*ray+1, fm), oz = ldf(orig_p, 3*ray+2, fm);
        const float vx = ldf(vec_p,  3*ray+0, fm), vy = ldf(vec_p,  3*ray+1, fm), vz = ldf(vec_p,  3*ray+2, fm);
        #pragma unroll
        for (int it = 0; it < 4; ++it) {
            const int gi = it * NRAYS + ray;
            bool mk;
            if      (ms == 1) mk = ((const uint8_t*) masks_p)[gi] != 0;
            else if (ms == 2) mk = ((const uint16_t*)masks_p)[gi] != 0;
            else              mk = ((const unsigned*) masks_p)[gi] != 0;
            const float tt1 = ldf(t1_p, gi, fm), tt2 = ldf(t2_p, gi, fm);
            const float dt = tt2 - tt1;
            sX[it][0][L] = (fmaf(vx, tt1, ox) - mn0) * is0;
            sX[it][1][L] = (fmaf(vy, tt1, oy) - mn1) * is1;
            sX[it][2][L] = (fmaf(vz, tt1, oz) - mn2) * is2;
            sX[it][3][L] = (vx * dt) * is0;
            sX[it][4][L] = (vy * dt) * is1;
            sX[it][5][L] = (vz * dt) * is2;
            sCT[it][L] = tt1;
            sMK[it][L] = mk ? 1.f : 0.f;
        }
        sDf[L] = INFV;
    }
    __syncthreads();

    #pragma unroll 1
    for (int rt = 0; rt < 4; ++rt) {
        #pragma unroll
        for (int ip = 0; ip < 2; ++ip) {
            f32x4 acc[2][4];
            short8 Ah[2], Am[2], Al[2];

            // ---------- Layer 0 (k=6 collapsed) ----------
            #pragma unroll
            for (int itl = 0; itl < 2; ++itl)
                #pragma unroll
                for (int ct = 0; ct < 4; ++ct) { f32x4 a; a[0]=a[1]=a[2]=a[3]=b0v[ct]; acc[itl][ct]=a; }

            #pragma unroll
            for (int itl = 0; itl < 2; ++itl) {
                const int it = ip * 2 + itl;
                int him[6], lo[6];
                #pragma unroll
                for (int j = 0; j < 6; ++j) {
                    float xv = sX[it][j][rt * 16 + c];   // uniform-flow LDS read (was bpermute)
                    split3(q == 0 ? xv : 0.f, him[j], lo[j]);
                }
                Ah[itl] = mk8i(PKLO(him[0],him[1]), PKLO(him[2],him[3]), PKLO(him[4],him[5]), 0);
                Am[itl] = mk8i(PKHI(him[0],him[1]), PKHI(him[2],him[3]), PKHI(him[4],him[5]), 0);
                Al[itl] = mk8i(PKLO(lo[0], lo[1]),  PKLO(lo[2], lo[3]),  PKLO(lo[4], lo[5]),  0);
            }
            #pragma unroll
            for (int ct = 0; ct < 4; ++ct) {
                short8 Bh = (q==0) ? ld_frag(wsu + FB0 + ((ct*3+0)*16 + c)*4) : mk8i(0,0,0,0);
                short8 Bm = (q==0) ? ld_frag(wsu + FB0 + ((ct*3+1)*16 + c)*4) : mk8i(0,0,0,0);
                short8 Bl = (q==0) ? ld_frag(wsu + FB0 + ((ct*3+2)*16 + c)*4) : mk8i(0,0,0,0);
                #pragma unroll
                for (int itl = 0; itl < 2; ++itl) {
                    acc[itl][ct] = __builtin_amdgcn_mfma_f32_16x16x32_bf16(Ah[itl], Bh, acc[itl][ct], 0,0,0);
                    acc[itl][ct] = __builtin_amdgcn_mfma_f32_16x16x32_bf16(Ah[itl], Bm, acc[itl][ct], 0,0,0);
                    acc[itl][ct] = __builtin_amdgcn_mfma_f32_16x16x32_bf16(Am[itl], Bh, acc[itl][ct], 0,0,0);
                    acc[itl][ct] = __builtin_amdgcn_mfma_f32_16x16x32_bf16(Am[itl], Bm, acc[itl][ct], 0,0,0);
                    acc[itl][ct] = __builtin_amdgcn_mfma_f32_16x16x32_bf16(Ah[itl], Bl, acc[itl][ct], 0,0,0);
                    acc[itl][ct] = __builtin_amdgcn_mfma_f32_16x16x32_bf16(Al[itl], Bh, acc[itl][ct], 0,0,0);
                }
            }

            // ---------- relu -> LN -> stage -> matmul (x2 layers) ----------
            #pragma unroll
            for (int layer = 0; layer < 2; ++layer) {
                const float* gv = layer ? g2v : g1v;
                const float* hv = layer ? h2v : h1v;
                const float* bv = layer ? s1v : s0v;
                const unsigned* fb = wsu + FB1 + layer * 6144;

                __syncthreads();
                #pragma unroll
                for (int itl = 0; itl < 2; ++itl) {
                    float z[4][4], mu[4], rs[4];
                    #pragma unroll
                    for (int ct = 0; ct < 4; ++ct)
                        #pragma unroll
                        for (int e = 0; e < 4; ++e) z[ct][e] = fmaxf(acc[itl][ct][e], 0.f);
                    #pragma unroll
                    for (int e = 0; e < 4; ++e) {
                        float s = z[0][e] + z[1][e] + z[2][e] + z[3][e];
                        mu[e] = rsum16(s) * (1.0f / 64.0f);
                    }
                    #pragma unroll
                    for (int e = 0; e < 4; ++e) {
                        float d0 = z[0][e]-mu[e], d1 = z[1][e]-mu[e], d2 = z[2][e]-mu[e], d3 = z[3][e]-mu[e];
                        float vv = fmaf(d3,d3, fmaf(d2,d2, fmaf(d1,d1, d0*d0)));
                        vv = rsum16(vv);
                        rs[e] = rsqrtf(fmaf(vv, 1.0f / 64.0f, 1e-5f));
                    }
                    int him[4][4], lov[4][4];
                    #pragma unroll
                    for (int ct = 0; ct < 4; ++ct)
                        #pragma unroll
                        for (int e = 0; e < 4; ++e) {
                            float y = fmaf((z[ct][e] - mu[e]) * rs[e], gv[ct], hv[ct]);
                            split3(y, him[ct][e], lov[ct][e]);
                        }
                    #pragma unroll
                    for (int e = 0; e < 4; ++e) {
                        int row = q * 4 + e;
                        #pragma unroll
                        for (int ct = 0; ct < 4; ++ct) sT1[itl][row][c + 16*ct] = (unsigned)him[ct][e];
                        sT2[itl][row][c]      = (unsigned)PKLO(lov[0][e], lov[2][e]);
                        sT2[itl][row][c + 16] = (unsigned)PKLO(lov[1][e], lov[3][e]);
                    }
                }
                __syncthreads();

                #pragma unroll
                for (int itl = 0; itl < 2; ++itl)
                    #pragma unroll
                    for (int ct = 0; ct < 4; ++ct) { f32x4 a; a[0]=a[1]=a[2]=a[3]=bv[ct]; acc[itl][ct]=a; }

                #pragma unroll
                for (int kc = 0; kc < 2; ++kc) {
                    #pragma unroll
                    for (int itl = 0; itl < 2; ++itl) {
                        const int4 w01 = *(const int4*)&sT1[itl][c][kc*32 + q*8];
                        const int4 w23 = *(const int4*)&sT1[itl][c][kc*32 + q*8 + 4];
                        const int4 t01 = *(const int4*)&sT2[itl][c][q*8];
                        const int4 t23 = *(const int4*)&sT2[itl][c][q*8 + 4];
                        Ah[itl] = mk8i(PKLO(w01.x,w01.y), PKLO(w01.z,w01.w), PKLO(w23.x,w23.y), PKLO(w23.z,w23.w));
                        Am[itl] = mk8i(PKHI(w01.x,w01.y), PKHI(w01.z,w01.w), PKHI(w23.x,w23.y), PKHI(w23.z,w23.w));
                        Al[itl] = (kc == 0)
                            ? mk8i(PKLO(t01.x,t01.y), PKLO(t01.z,t01.w), PKLO(t23.x,t23.y), PKLO(t23.z,t23.w))
                            : mk8i(PKHI(t01.x,t01.y), PKHI(t01.z,t01.w), PKHI(t23.x,t23.y), PKHI(t23.z,t23.w));
                    }
                    #pragma unroll
                    for (int ct = 0; ct < 4; ++ct) {
                        short8 Bh = ld_frag(fb + (((ct*2+kc)*3 + 0) << 8) + (L << 2));
                        short8 Bm = ld_frag(fb + (((ct*2+kc)*3 + 1) << 8) + (L << 2));
                        short8 Bl = ld_frag(fb + (((ct*2+kc)*3 + 2) << 8) + (L << 2));
                        #pragma unroll
                        for (int itl = 0; itl < 2; ++itl) {
                            acc[itl][ct] = __builtin_amdgcn_mfma_f32_16x16x32_bf16(Ah[itl], Bh, acc[itl][ct], 0,0,0);
                            acc[itl][ct] = __builtin_amdgcn_mfma_f32_16x16x32_bf16(Ah[itl], Bm, acc[itl][ct], 0,0,0);
                            acc[itl][ct] = __builtin_amdgcn_mfma_f32_16x16x32_bf16(Am[itl], Bh, acc[itl][ct], 0,0,0);
                            acc[itl][ct] = __builtin_amdgcn_mfma_f32_16x16x32_bf16(Am[itl], Bm, acc[itl][ct], 0,0,0);
                            acc[itl][ct] = __builtin_amdgcn_mfma_f32_16x16x32_bf16(Ah[itl], Bl, acc[itl][ct], 0,0,0);
                            acc[itl][ct] = __builtin_amdgcn_mfma_f32_16x16x32_bf16(Al[itl], Bh, acc[itl][ct], 0,0,0);
                        }
                    }
                }
            }

            // ---------- heads + dist update (C/D layout) ----------
            #pragma unroll
            for (int e = 0; e < 4; ++e) {
                const int idx = rt * 16 + q * 4 + e;
                float d = sDf[idx];
                #pragma unroll
                for (int itl = 0; itl < 2; ++itl) {
                    const int it = ip * 2 + itl;
                    float cp = 0.f, dp = 0.f;
                    #pragma unroll
                    for (int ct = 0; ct < 4; ++ct) {
                        float f = fmaxf(acc[itl][ct][e], 0.f);
                        cp = fmaf(f, wcv[ct], cp);
                        dp = fmaf(f, wdv[ct], dp);
                    }
                    cp = rsum16(cp); dp = rsum16(dp);
                    float cls = cp + bcv;
                    float t1v = sCT[it][idx];   // 16-lane broadcast read
                    float mkv = sMK[it][idx];
                    float dv  = dp + bdv + t1v;
                    if (mkv > 0.5f && cls > 0.f && dv < d) d = dv;
                }
                if (c == 0) sDf[idx] = d;
            }
        }
    }

    __syncthreads();
    float d = sDf[L];
    if (d == INFV) d = 0.f;
    const float hit = (d > 0.f) ? 1.f : 0.f;
    if (fm) {
        ((float*)out_p)[ray]         = hit;
        ((float*)out_p)[NRAYS + ray] = d;
    } else {
        __hip_bfloat16* o = (__hip_bfloat16*)out_p;
        o[ray]         = __float2bfloat16(hit);
        o[NRAYS + ray] = __float2bfloat16(d);
    }
}

extern "C" void kernel_launch(void* const* d_in, const int* in_sizes, int n_in,
                              void* d_out, int out_size, void* d_ws, size_t ws_size,
                              hipStream_t stream) {
    (void)in_sizes; (void)n_in; (void)ws_size; (void)out_size;
    unsigned* ws = (unsigned*)d_ws;
    conv_k<<<1, 256, 0, stream>>>(
        d_in[6], d_in[7], d_in[2],
        d_in[8], d_in[9], d_in[10], d_in[11],
        d_in[12], d_in[13], d_in[14], d_in[15],
        d_in[16], d_in[17], ws);
    nbvh_main<<<NRAYS / 64, 64, 0, stream>>>(
        d_in[0], d_in[1], d_in[2], d_in[4], d_in[5], ws, d_out);
}

// Round 8
// 826.409 us; speedup vs baseline: 1.9886x; 1.2274x over previous
//
#include <hip/hip_runtime.h>
#include <hip/hip_bf16.h>
#include <stdint.h>

#define NRAYS 1048576
#define INFV  1e9f
#define TBIG  1e30f

typedef short short8 __attribute__((ext_vector_type(8)));
typedef float f32x4  __attribute__((ext_vector_type(4)));

// ---- d_ws u32 layout ----
#define WS_B0   16
#define FB0     1024   // L0 frags: 4ct*3h*16lane*4 = 768 u32 (quad0 only)
#define FB1     2048   // L1+L2 frags: 12288 u32

#define PKLO(a,b) ((int)(((unsigned)(a) & 0xFFFFu) | ((unsigned)(b) << 16)))
#define PKHI(a,b) ((int)(((unsigned)(a) >> 16) | ((unsigned)(b) & 0xFFFF0000u)))

__device__ __forceinline__ float ldf(const void* p, int i, int fm) {
    if (fm) return ((const float*)p)[i];
    unsigned u = ((const unsigned short*)p)[i];
    return __uint_as_float(u << 16);
}

__device__ __forceinline__ void split3(float f, int& him, int& lo) {
    unsigned u = __float_as_uint(f);
    float r = f - __uint_as_float(u & 0xFFFF0000u);
    unsigned um = __float_as_uint(r);
    float r2 = r - __uint_as_float(um & 0xFFFF0000u);
    unsigned ul = __float_as_uint(r2);
    him = (int)((u >> 16) | (um & 0xFFFF0000u));
    lo  = (int)(ul >> 16);
}

__device__ __forceinline__ unsigned comp16(int h, float f) {
    unsigned u = __float_as_uint(f);
    if (h == 0) return u >> 16;
    float r = f - __uint_as_float(u & 0xFFFF0000u);
    unsigned um = __float_as_uint(r);
    if (h == 1) return um >> 16;
    float r2 = r - __uint_as_float(um & 0xFFFF0000u);
    return __float_as_uint(r2) >> 16;
}

__device__ __forceinline__ float rsum16(float x) {
    int v;
    v = __builtin_amdgcn_update_dpp(0, __float_as_int(x), 0x128, 0xF, 0xF, false); x += __int_as_float(v);
    v = __builtin_amdgcn_update_dpp(0, __float_as_int(x), 0x124, 0xF, 0xF, false); x += __int_as_float(v);
    v = __builtin_amdgcn_update_dpp(0, __float_as_int(x), 0x122, 0xF, 0xF, false); x += __int_as_float(v);
    v = __builtin_amdgcn_update_dpp(0, __float_as_int(x), 0x121, 0xF, 0xF, false); x += __int_as_float(v);
    return x;
}

union I4S8 { int4 i; short8 s; };
__device__ __forceinline__ short8 mk8i(int a, int b, int c, int d) {
    I4S8 u; u.i = make_int4(a, b, c, d); return u.s;
}
__device__ __forceinline__ short8 ld_frag(const unsigned* p) {
    I4S8 u; u.i = *(const int4*)p; return u.s;
}

// ---------------- prologue (unchanged — validated) ----------------
__global__ __launch_bounds__(256) void conv_k(
    const void* __restrict__ mmin, const void* __restrict__ mmax,
    const void* __restrict__ masks,
    const void* __restrict__ W0, const void* __restrict__ b0,
    const void* __restrict__ lng, const void* __restrict__ lnb,
    const void* __restrict__ Ws, const void* __restrict__ bs,
    const void* __restrict__ Wc, const void* __restrict__ bc,
    const void* __restrict__ Wd, const void* __restrict__ bd,
    unsigned* __restrict__ ws)
{
    __shared__ int sfm;
    float* wf = (float*)ws;
    const int tid = threadIdx.x;
    if (tid == 0) {
        unsigned w0 = ((const unsigned*)mmin)[0];
        int fm = ((w0 & 0xFFFFu) == 0u) ? 1 : 0;
        const unsigned* mw = (const unsigned*)masks;
        bool sawBf = false, allBin = true, sawF32 = false;
        for (int i = 0; i < 64; ++i) {
            unsigned w = mw[i], lo = w & 0xFFFFu, hi = w >> 16;
            if (lo == 0x3F80u && (hi == 0x3F80u || hi == 0u)) sawBf = true;
            if (w == 0x3F800000u) sawF32 = true;
            if (w > 1u) allBin = false;
        }
        int ms = sawBf ? 2 : (allBin ? 4 : (sawF32 ? 4 : 1));
        ws[8] = (unsigned)fm; ws[9] = (unsigned)ms;
        for (int c = 0; c < 3; ++c) {
            float mn = ldf(mmin, c, fm), mx = ldf(mmax, c, fm);
            float ext = mx - mn;
            wf[c]     = mn - 0.5f * ext;
            wf[3 + c] = 1.0f / (2.0f * ext);
        }
        wf[6] = ldf(bc, 0, fm);
        wf[7] = ldf(bd, 0, fm);
        sfm = fm;
    }
    __syncthreads();
    const int fm = sfm;

    for (int i = tid; i < 64;  i += 256) { wf[16 + i] = ldf(b0, i, fm); wf[464 + i] = ldf(Wc, i, fm); wf[528 + i] = ldf(Wd, i, fm); }
    for (int i = tid; i < 128; i += 256) { wf[80 + i] = ldf(bs, i, fm); wf[208 + i] = ldf(lng, i, fm); wf[336 + i] = ldf(lnb, i, fm); }

    for (int w = tid; w < 768; w += 256) {
        int ct = w / 192, rem = w % 192;
        int h = rem / 64, wi = rem % 64;
        int lane16 = wi >> 2, p = wi & 3;
        int n = ct * 16 + lane16;
        unsigned word = 0;
        #pragma unroll
        for (int half = 0; half < 2; ++half) {
            int k = 2 * p + half;
            float v = 0.f;
            if (k < 3) {
                for (int pp = 0; pp < 8; ++pp) v += ldf(W0, (3 * pp + k) * 64 + n, fm);
            } else if (k < 6) {
                int c3 = k - 3;
                for (int pp = 0; pp < 8; ++pp) v = fmaf((float)((double)pp / 7.0), ldf(W0, (3 * pp + c3) * 64 + n, fm), v);
            }
            word |= comp16(h, v) << (16 * half);
        }
        ws[FB0 + ((ct * 3 + h) * 16 + lane16) * 4 + p] = word;
    }

    for (int w = tid; w < 12288; w += 256) {
        int li = w / 6144, inner = w % 6144;
        int t = inner >> 8;
        int h = t % 3, ckc = t / 3, kc = ckc & 1, ct = ckc >> 1;
        int wi = inner & 255, lane = wi >> 2, p = wi & 3;
        int qq = lane >> 4, cc = lane & 15;
        int n = ct * 16 + cc;
        int k0 = kc * 32 + qq * 8 + 2 * p;
        float f0 = ldf(Ws, li * 4096 + k0 * 64 + n, fm);
        float f1 = ldf(Ws, li * 4096 + (k0 + 1) * 64 + n, fm);
        ws[FB1 + w] = comp16(h, f0) | (comp16(h, f1) << 16);
    }
}

// ---------------- main: 64 rays/wave, MFMA bf16x3; LDS cut to ~12.5 KB for
// 12 blocks/CU (3 waves/SIMD); single-itl transpose buffer, A-frags pre-built ----------------
#define ST1_S 66
#define ST2_S 34

__global__ __launch_bounds__(64, 3) void nbvh_main(
    const void* __restrict__ orig_p, const void* __restrict__ vec_p,
    const void* __restrict__ masks_p, const void* __restrict__ t1_p,
    const void* __restrict__ t2_p, const unsigned* __restrict__ wsu,
    void* __restrict__ out_p)
{
    __shared__ __align__(16) unsigned sT1[16][ST1_S];  // 4224 B (single itl)
    __shared__ __align__(16) unsigned sT2[16][ST2_S];  // 2176 B
    __shared__ float sOV[6][64];    // pre-normalized o',v' (1536 B)
    __shared__ float sT1m[4][64];   // t1 or 1e30 if masked (1024 B)
    __shared__ float sT2g[4][64];   // t2 (1024 B)
    __shared__ float sB[576];       // b0|bs0|bs1|g1|g2|h1|h2|wc|wd (2304 B)
    __shared__ float sDf[64];       // 256 B

    const float* wf = (const float*)wsu;
    const int fm = (int)wsu[8];
    const int ms = (int)wsu[9];
    const float bcv = wf[6], bdv = wf[7];

    const int L = threadIdx.x;
    const int q = L >> 4, c = L & 15;
    const int ray = blockIdx.x * 64 + L;

    for (int i = L; i < 576; i += 64) sB[i] = wf[16 + i];

    {
        const float mn0 = wf[0], mn1 = wf[1], mn2 = wf[2];
        const float is0 = wf[3], is1 = wf[4], is2 = wf[5];
        const float o0 = ldf(orig_p, 3*ray+0, fm), o1 = ldf(orig_p, 3*ray+1, fm), o2 = ldf(orig_p, 3*ray+2, fm);
        const float v0 = ldf(vec_p,  3*ray+0, fm), v1 = ldf(vec_p,  3*ray+1, fm), v2 = ldf(vec_p,  3*ray+2, fm);
        sOV[0][L] = (o0 - mn0) * is0;  sOV[1][L] = (o1 - mn1) * is1;  sOV[2][L] = (o2 - mn2) * is2;
        sOV[3][L] = v0 * is0;          sOV[4][L] = v1 * is1;          sOV[5][L] = v2 * is2;
        #pragma unroll
        for (int it = 0; it < 4; ++it) {
            const int gi = it * NRAYS + ray;
            bool mk;
            if      (ms == 1) mk = ((const uint8_t*) masks_p)[gi] != 0;
            else if (ms == 2) mk = ((const uint16_t*)masks_p)[gi] != 0;
            else              mk = ((const unsigned*) masks_p)[gi] != 0;
            sT1m[it][L] = mk ? ldf(t1_p, gi, fm) : TBIG;   // masked -> dv ~1e30, never selected
            sT2g[it][L] = ldf(t2_p, gi, fm);
        }
        sDf[L] = INFV;
    }
    __syncthreads();

    #pragma unroll 1
    for (int rt = 0; rt < 4; ++rt) {
        #pragma unroll 1
        for (int ip = 0; ip < 2; ++ip) {
            f32x4 acc[2][4];
            short8 Ah[2][2], Am[2][2], Al[2][2];   // [itl][kc]

            // ---------- Layer 0: A from recomputed x (k=6 collapsed) ----------
            {
                short8 Xh[2], Xm[2], Xl[2];
                #pragma unroll
                for (int itl = 0; itl < 2; ++itl) {
                    const int it = ip * 2 + itl;
                    const int row = rt * 16 + c;
                    const float t1v = sT1m[it][row];
                    const float dtv = sT2g[it][row] - t1v;
                    float x[6];
                    #pragma unroll
                    for (int j = 0; j < 3; ++j) {
                        float ov = sOV[j][row], vv = sOV[3 + j][row];
                        x[j]     = fmaf(vv, t1v, ov);
                        x[3 + j] = vv * dtv;
                    }
                    int him[6], lo[6];
                    #pragma unroll
                    for (int j = 0; j < 6; ++j) split3(q == 0 ? x[j] : 0.f, him[j], lo[j]);
                    Xh[itl] = mk8i(PKLO(him[0],him[1]), PKLO(him[2],him[3]), PKLO(him[4],him[5]), 0);
                    Xm[itl] = mk8i(PKHI(him[0],him[1]), PKHI(him[2],him[3]), PKHI(him[4],him[5]), 0);
                    Xl[itl] = mk8i(PKLO(lo[0], lo[1]),  PKLO(lo[2], lo[3]),  PKLO(lo[4], lo[5]),  0);
                }
                #pragma unroll
                for (int itl = 0; itl < 2; ++itl)
                    #pragma unroll
                    for (int ct = 0; ct < 4; ++ct) {
                        float b = sB[ct * 16 + c];
                        f32x4 a; a[0]=a[1]=a[2]=a[3]=b; acc[itl][ct]=a;
                    }
                #pragma unroll
                for (int ct = 0; ct < 4; ++ct) {
                    short8 Bh = (q==0) ? ld_frag(wsu + FB0 + ((ct*3+0)*16 + c)*4) : mk8i(0,0,0,0);
                    short8 Bm = (q==0) ? ld_frag(wsu + FB0 + ((ct*3+1)*16 + c)*4) : mk8i(0,0,0,0);
                    short8 Bl = (q==0) ? ld_frag(wsu + FB0 + ((ct*3+2)*16 + c)*4) : mk8i(0,0,0,0);
                    #pragma unroll
                    for (int itl = 0; itl < 2; ++itl) {
                        acc[itl][ct] = __builtin_amdgcn_mfma_f32_16x16x32_bf16(Xh[itl], Bh, acc[itl][ct], 0,0,0);
                        acc[itl][ct] = __builtin_amdgcn_mfma_f32_16x16x32_bf16(Xh[itl], Bm, acc[itl][ct], 0,0,0);
                        acc[itl][ct] = __builtin_amdgcn_mfma_f32_16x16x32_bf16(Xm[itl], Bh, acc[itl][ct], 0,0,0);
                        acc[itl][ct] = __builtin_amdgcn_mfma_f32_16x16x32_bf16(Xm[itl], Bm, acc[itl][ct], 0,0,0);
                        acc[itl][ct] = __builtin_amdgcn_mfma_f32_16x16x32_bf16(Xh[itl], Bl, acc[itl][ct], 0,0,0);
                        acc[itl][ct] = __builtin_amdgcn_mfma_f32_16x16x32_bf16(Xl[itl], Bh, acc[itl][ct], 0,0,0);
                    }
                }
            }

            // ---------- layers: LN -> stage(single buffer) -> build A; then matmul ----------
            #pragma unroll 1
            for (int layer = 0; layer < 2; ++layer) {
                const unsigned* fb = wsu + FB1 + layer * 6144;
                const int bo = 64 + layer * 64, go = 192 + layer * 64, ho = 320 + layer * 64;

                #pragma unroll
                for (int itl = 0; itl < 2; ++itl) {
                    __syncthreads();   // previous itl's A-build reads done
                    float z[4][4];
                    #pragma unroll
                    for (int ct = 0; ct < 4; ++ct)
                        #pragma unroll
                        for (int e = 0; e < 4; ++e) z[ct][e] = fmaxf(acc[itl][ct][e], 0.f);
                    float mu[4], rs[4];
                    #pragma unroll
                    for (int e = 0; e < 4; ++e) {
                        float s  = z[0][e] + z[1][e] + z[2][e] + z[3][e];
                        float s2 = fmaf(z[0][e], z[0][e], fmaf(z[1][e], z[1][e],
                                   fmaf(z[2][e], z[2][e], z[3][e] * z[3][e])));
                        s  = rsum16(s);    // two independent DPP chains interleave
                        s2 = rsum16(s2);
                        mu[e] = s * (1.0f / 64.0f);
                        float var = fmaf(-mu[e], mu[e], s2 * (1.0f / 64.0f));
                        rs[e] = rsqrtf(var + 1e-5f);
                    }
                    int him[4][4], lov[4][4];
                    #pragma unroll
                    for (int ct = 0; ct < 4; ++ct) {
                        const float gv = sB[go + ct * 16 + c];
                        const float hv = sB[ho + ct * 16 + c];
                        #pragma unroll
                        for (int e = 0; e < 4; ++e) {
                            float y = fmaf((z[ct][e] - mu[e]) * rs[e], gv, hv);
                            split3(y, him[ct][e], lov[ct][e]);
                        }
                    }
                    #pragma unroll
                    for (int e = 0; e < 4; ++e) {
                        const int row = q * 4 + e;
                        #pragma unroll
                        for (int ct = 0; ct < 4; ++ct) sT1[row][c + 16*ct] = (unsigned)him[ct][e];
                        sT2[row][c]      = (unsigned)PKLO(lov[0][e], lov[2][e]);
                        sT2[row][c + 16] = (unsigned)PKLO(lov[1][e], lov[3][e]);
                    }
                    __syncthreads();   // stores visible
                    const int4 t01 = *(const int4*)&sT2[c][q*8];
                    const int4 t23 = *(const int4*)&sT2[c][q*8 + 4];
                    #pragma unroll
                    for (int kc = 0; kc < 2; ++kc) {
                        const int4 w01 = *(const int4*)&sT1[c][kc*32 + q*8];
                        const int4 w23 = *(const int4*)&sT1[c][kc*32 + q*8 + 4];
                        Ah[itl][kc] = mk8i(PKLO(w01.x,w01.y), PKLO(w01.z,w01.w), PKLO(w23.x,w23.y), PKLO(w23.z,w23.w));
                        Am[itl][kc] = mk8i(PKHI(w01.x,w01.y), PKHI(w01.z,w01.w), PKHI(w23.x,w23.y), PKHI(w23.z,w23.w));
                        Al[itl][kc] = (kc == 0)
                            ? mk8i(PKLO(t01.x,t01.y), PKLO(t01.z,t01.w), PKLO(t23.x,t23.y), PKLO(t23.z,t23.w))
                            : mk8i(PKHI(t01.x,t01.y), PKHI(t01.z,t01.w), PKHI(t23.x,t23.y), PKHI(t23.z,t23.w));
                    }
                }

                #pragma unroll
                for (int itl = 0; itl < 2; ++itl)
                    #pragma unroll
                    for (int ct = 0; ct < 4; ++ct) {
                        float b = sB[bo + ct * 16 + c];
                        f32x4 a; a[0]=a[1]=a[2]=a[3]=b; acc[itl][ct]=a;
                    }
                #pragma unroll
                for (int kc = 0; kc < 2; ++kc) {
                    #pragma unroll
                    for (int ct = 0; ct < 4; ++ct) {
                        short8 Bh = ld_frag(fb + (((ct*2+kc)*3 + 0) << 8) + (L << 2));
                        short8 Bm = ld_frag(fb + (((ct*2+kc)*3 + 1) << 8) + (L << 2));
                        short8 Bl = ld_frag(fb + (((ct*2+kc)*3 + 2) << 8) + (L << 2));
                        #pragma unroll
                        for (int itl = 0; itl < 2; ++itl) {
                            acc[itl][ct] = __builtin_amdgcn_mfma_f32_16x16x32_bf16(Ah[itl][kc], Bh, acc[itl][ct], 0,0,0);
                            acc[itl][ct] = __builtin_amdgcn_mfma_f32_16x16x32_bf16(Ah[itl][kc], Bm, acc[itl][ct], 0,0,0);
                            acc[itl][ct] = __builtin_amdgcn_mfma_f32_16x16x32_bf16(Am[itl][kc], Bh, acc[itl][ct], 0,0,0);
                            acc[itl][ct] = __builtin_amdgcn_mfma_f32_16x16x32_bf16(Am[itl][kc], Bm, acc[itl][ct], 0,0,0);
                            acc[itl][ct] = __builtin_amdgcn_mfma_f32_16x16x32_bf16(Ah[itl][kc], Bl, acc[itl][ct], 0,0,0);
                            acc[itl][ct] = __builtin_amdgcn_mfma_f32_16x16x32_bf16(Al[itl][kc], Bh, acc[itl][ct], 0,0,0);
                        }
                    }
                }
            }

            // ---------- heads + dist update (C/D layout) ----------
            {
                float wcr[4], wdr[4];
                #pragma unroll
                for (int ct = 0; ct < 4; ++ct) {
                    wcr[ct] = sB[448 + ct * 16 + c];
                    wdr[ct] = sB[512 + ct * 16 + c];
                }
                #pragma unroll
                for (int e = 0; e < 4; ++e) {
                    const int idx = rt * 16 + q * 4 + e;
                    float d = sDf[idx];
                    #pragma unroll
                    for (int itl = 0; itl < 2; ++itl) {
                        const int it = ip * 2 + itl;
                        float cp = 0.f, dp = 0.f;
                        #pragma unroll
                        for (int ct = 0; ct < 4; ++ct) {
                            float f = fmaxf(acc[itl][ct][e], 0.f);
                            cp = fmaf(f, wcr[ct], cp);
                            dp = fmaf(f, wdr[ct], dp);
                        }
                        cp = rsum16(cp); dp = rsum16(dp);
                        float cls = cp + bcv;
                        float dv  = dp + bdv + sT1m[it][idx];   // masked -> +1e30
                        if (cls > 0.f && dv < d) d = dv;
                    }
                    if (c == 0) sDf[idx] = d;
                }
            }
        }
    }

    __syncthreads();
    float d = sDf[L];
    if (d == INFV) d = 0.f;
    const float hit = (d > 0.f) ? 1.f : 0.f;
    if (fm) {
        ((float*)out_p)[ray]         = hit;
        ((float*)out_p)[NRAYS + ray] = d;
    } else {
        __hip_bfloat16* o = (__hip_bfloat16*)out_p;
        o[ray]         = __float2bfloat16(hit);
        o[NRAYS + ray] = __float2bfloat16(d);
    }
}

extern "C" void kernel_launch(void* const* d_in, const int* in_sizes, int n_in,
                              void* d_out, int out_size, void* d_ws, size_t ws_size,
                              hipStream_t stream) {
    (void)in_sizes; (void)n_in; (void)ws_size; (void)out_size;
    unsigned* ws = (unsigned*)d_ws;
    conv_k<<<1, 256, 0, stream>>>(
        d_in[6], d_in[7], d_in[2],
        d_in[8], d_in[9], d_in[10], d_in[11],
        d_in[12], d_in[13], d_in[14], d_in[15],
        d_in[16], d_in[17], ws);
    nbvh_main<<<NRAYS / 64, 64, 0, stream>>>(
        d_in[0], d_in[1], d_in[2], d_in[4], d_in[5], ws, d_out);
}